// Round 7
// baseline (669.696 us; speedup 1.0000x reference)
//
#include <hip/hip_runtime.h>

#define I_DIM 16
#define H_DIM 32
#define T_DIM 512
#define B_DIM 4096

__device__ __forceinline__ float fast_tanh(float x) {
    // tanh(x) = 1 - 2/(exp(2x)+1); exp(2x) = exp2(x * 2*log2(e))
    float e = __builtin_amdgcn_exp2f(x * 2.885390081777927f);
    return 1.0f - 2.0f * __builtin_amdgcn_rcpf(e + 1.0f);
}

// One batch row per 64-lane wave. Element j = lane&31; k-half kh = lane>>5.
// Each lane holds the kh-half (16 floats) of its weight rows and of h1/h2.
// Cross-half reduce: one __shfl_xor(.,32) per layer. 4096 waves = 16/CU.
__global__ void __launch_bounds__(256, 4)
rnn2_splitk_kernel(const float* __restrict__ x,
                   const float* __restrict__ Wih0, const float* __restrict__ Whh0,
                   const float* __restrict__ bih0, const float* __restrict__ bhh0,
                   const float* __restrict__ Wih1, const float* __restrict__ Whh1,
                   const float* __restrict__ bih1, const float* __restrict__ bhh1,
                   const float* __restrict__ fcw, const float* __restrict__ fcb,
                   float* __restrict__ out)
{
    const int tid  = threadIdx.x;
    const int lane = tid & 63;
    const int wid  = tid >> 6;        // wave in block: 0..3
    const int j    = lane & 31;       // output element
    const int kh   = lane >> 5;       // k-half: 0 or 1
    const int batch = blockIdx.x * 4 + wid;

    // [64]-wide rows: kh=1 lanes write a dummy upper copy -> no divergence,
    // no same-address write collisions. Canonical h lives at [0..31].
    __shared__ __align__(16) float sh1[4][64];
    __shared__ __align__(16) float sh2[4][64];
    float* s1p = sh1[wid];
    float* s2p = sh2[wid];

    // ---- per-lane half weight rows (registers) ----
    float whh0h[16], wih1h[16], whh1h[16], wih0h[8];
#pragma unroll
    for (int q = 0; q < 4; ++q) {
        float4 a = reinterpret_cast<const float4*>(Whh0 + j * 32 + kh * 16)[q];
        whh0h[4*q+0] = a.x; whh0h[4*q+1] = a.y; whh0h[4*q+2] = a.z; whh0h[4*q+3] = a.w;
        float4 b = reinterpret_cast<const float4*>(Wih1 + j * 32 + kh * 16)[q];
        wih1h[4*q+0] = b.x; wih1h[4*q+1] = b.y; wih1h[4*q+2] = b.z; wih1h[4*q+3] = b.w;
        float4 c = reinterpret_cast<const float4*>(Whh1 + j * 32 + kh * 16)[q];
        whh1h[4*q+0] = c.x; whh1h[4*q+1] = c.y; whh1h[4*q+2] = c.z; whh1h[4*q+3] = c.w;
    }
#pragma unroll
    for (int q = 0; q < 2; ++q) {
        float4 v = reinterpret_cast<const float4*>(Wih0 + j * 16 + kh * 8)[q];
        wih0h[4*q+0] = v.x; wih0h[4*q+1] = v.y; wih0h[4*q+2] = v.z; wih0h[4*q+3] = v.w;
    }
    // bias seeded into kh==0 half only (shfl-sum counts it exactly once)
    const float b0seed = kh ? 0.f : (bih0[j] + bhh0[j]);
    const float b1seed = kh ? 0.f : (bih1[j] + bhh1[j]);

    const float* xrow = x + (size_t)batch * (T_DIM * I_DIM) + kh * 8;

    // half-vectors of the hidden states (this lane's k-range)
    float h1h[16], h2h[16];
#pragma unroll
    for (int k = 0; k < 16; ++k) { h1h[k] = 0.f; h2h[k] = 0.f; }

    // x(0) half
    float4 px0 = reinterpret_cast<const float4*>(xrow)[0];
    float4 px1 = reinterpret_cast<const float4*>(xrow)[1];

#pragma unroll 1
    for (int t = 0; t < T_DIM; ++t) {
        // prefetch x(t+1) half one iteration ahead
        const int tn = (t + 1 < T_DIM) ? (t + 1) : t;
        const float4* xp = reinterpret_cast<const float4*>(xrow + (size_t)tn * I_DIM);
        float4 nx0 = xp[0];
        float4 nx1 = xp[1];

        // ---- layer 0: s1 = bias0 + Wih0[j,:].x(t) + Whh0[j,:].h1(t-1), split over kh ----
        float a0 = b0seed, a1 = 0.f, a2 = 0.f, a3 = 0.f;
        a0 = fmaf(wih0h[0], px0.x, a0); a1 = fmaf(wih0h[1], px0.y, a1);
        a2 = fmaf(wih0h[2], px0.z, a2); a3 = fmaf(wih0h[3], px0.w, a3);
        a0 = fmaf(wih0h[4], px1.x, a0); a1 = fmaf(wih0h[5], px1.y, a1);
        a2 = fmaf(wih0h[6], px1.z, a2); a3 = fmaf(wih0h[7], px1.w, a3);
#pragma unroll
        for (int k = 0; k < 16; k += 4) {
            a0 = fmaf(whh0h[k+0], h1h[k+0], a0);
            a1 = fmaf(whh0h[k+1], h1h[k+1], a1);
            a2 = fmaf(whh0h[k+2], h1h[k+2], a2);
            a3 = fmaf(whh0h[k+3], h1h[k+3], a3);
        }
        float s1 = (a0 + a1) + (a2 + a3);
        s1 += __shfl_xor(s1, 32, 64);          // both halves now hold full sum
        float h1j = fast_tanh(s1);
        s1p[j + kh * 32] = h1j;                // kh=1 -> dummy copy at [32..63]
        __builtin_amdgcn_wave_barrier();
#pragma unroll
        for (int q = 0; q < 4; ++q) {          // re-gather this lane's k-half of h1(t)
            float4 v = reinterpret_cast<const float4*>(s1p + kh * 16)[q];
            h1h[4*q+0] = v.x; h1h[4*q+1] = v.y; h1h[4*q+2] = v.z; h1h[4*q+3] = v.w;
        }

        // ---- layer 1: s2 = bias1 + Wih1[j,:].h1(t) + Whh1[j,:].h2(t-1) ----
        float c0 = b1seed, c1 = 0.f, c2 = 0.f, c3 = 0.f;
#pragma unroll
        for (int k = 0; k < 16; k += 4) {
            c0 = fmaf(wih1h[k+0], h1h[k+0], c0);
            c1 = fmaf(wih1h[k+1], h1h[k+1], c1);
            c2 = fmaf(wih1h[k+2], h1h[k+2], c2);
            c3 = fmaf(wih1h[k+3], h1h[k+3], c3);
        }
#pragma unroll
        for (int k = 0; k < 16; k += 4) {
            c0 = fmaf(whh1h[k+0], h2h[k+0], c0);
            c1 = fmaf(whh1h[k+1], h2h[k+1], c1);
            c2 = fmaf(whh1h[k+2], h2h[k+2], c2);
            c3 = fmaf(whh1h[k+3], h2h[k+3], c3);
        }
        float s2 = (c0 + c1) + (c2 + c3);
        s2 += __shfl_xor(s2, 32, 64);
        float h2j = fast_tanh(s2);
        s2p[j + kh * 32] = h2j;
        __builtin_amdgcn_wave_barrier();
#pragma unroll
        for (int q = 0; q < 4; ++q) {          // this lane's k-half of h2(t)
            float4 v = reinterpret_cast<const float4*>(s2p + kh * 16)[q];
            h2h[4*q+0] = v.x; h2h[4*q+1] = v.y; h2h[4*q+2] = v.z; h2h[4*q+3] = v.w;
        }

        px0 = nx0; px1 = nx1;
    }

    // ---- final FC: logit = fc_w . h2(T-1) + fc_b (k split over kh) ----
    float fw[16];
#pragma unroll
    for (int q = 0; q < 4; ++q) {
        float4 v = reinterpret_cast<const float4*>(fcw + kh * 16)[q];
        fw[4*q+0] = v.x; fw[4*q+1] = v.y; fw[4*q+2] = v.z; fw[4*q+3] = v.w;
    }
    float r0 = 0.f, r1 = 0.f, r2 = 0.f, r3 = 0.f;
#pragma unroll
    for (int k = 0; k < 16; k += 4) {
        r0 = fmaf(fw[k+0], h2h[k+0], r0);
        r1 = fmaf(fw[k+1], h2h[k+1], r1);
        r2 = fmaf(fw[k+2], h2h[k+2], r2);
        r3 = fmaf(fw[k+3], h2h[k+3], r3);
    }
    float s = (r0 + r1) + (r2 + r3);
    s += __shfl_xor(s, 32, 64);
    if (lane == 0) out[batch] = s + fcb[0];
}

extern "C" void kernel_launch(void* const* d_in, const int* in_sizes, int n_in,
                              void* d_out, int out_size, void* d_ws, size_t ws_size,
                              hipStream_t stream) {
    const float* x    = (const float*)d_in[0];
    const float* Wih0 = (const float*)d_in[1];
    const float* Whh0 = (const float*)d_in[2];
    const float* bih0 = (const float*)d_in[3];
    const float* bhh0 = (const float*)d_in[4];
    const float* Wih1 = (const float*)d_in[5];
    const float* Whh1 = (const float*)d_in[6];
    const float* bih1 = (const float*)d_in[7];
    const float* bhh1 = (const float*)d_in[8];
    const float* fcw  = (const float*)d_in[9];
    const float* fcb  = (const float*)d_in[10];
    float* out = (float*)d_out;

    dim3 grid(B_DIM / 4);   // 1024 blocks x 4 waves = 4096 waves, one batch row each
    rnn2_splitk_kernel<<<grid, 256, 0, stream>>>(x, Wih0, Whh0, bih0, bhh0,
                                                 Wih1, Whh1, bih1, bhh1,
                                                 fcw, fcb, out);
}

// Round 8
// 325.757 us; speedup vs baseline: 2.0558x; 2.0558x over previous
//
#include <hip/hip_runtime.h>

#define I_DIM 16
#define H_DIM 32
#define T_DIM 512
#define B_DIM 4096

__device__ __forceinline__ float fast_tanh(float x) {
    // tanh(x) = 1 - 2/(exp(2x)+1); exp(2x) = exp2(x * 2*log2(e))
    float e = __builtin_amdgcn_exp2f(x * 2.885390081777927f);
    return 1.0f - 2.0f * __builtin_amdgcn_rcpf(e + 1.0f);
}

// One batch row per 32-lane half-wave (round-6 decomposition, measured best).
// Cross-layer pipeline: iteration t computes h1(t+1) AND h2(t), both from
// h1(t)/h2(t-1), so the serial chain is max(L0,L1) not L0+L1, and both
// transposes share ONE LDS write->barrier->read phase.
// amdgpu_waves_per_eu(2,2): pin 2 waves/SIMD so the compiler keeps all 112
// weight floats register-resident instead of reloading from L1 every step.
__global__ void __launch_bounds__(256)
__attribute__((amdgpu_waves_per_eu(2, 2)))
rnn2_pipe_kernel(const float* __restrict__ x,
                 const float* __restrict__ Wih0, const float* __restrict__ Whh0,
                 const float* __restrict__ bih0, const float* __restrict__ bhh0,
                 const float* __restrict__ Wih1, const float* __restrict__ Whh1,
                 const float* __restrict__ bih1, const float* __restrict__ bhh1,
                 const float* __restrict__ fcw, const float* __restrict__ fcb,
                 float* __restrict__ out)
{
    const int tid  = threadIdx.x;
    const int j    = tid & 31;        // output row within H
    const int half = tid >> 5;        // 0..7: batch element within block
    const int batch = blockIdx.x * 8 + half;

    __shared__ __align__(16) float sh1[8][32];
    __shared__ __align__(16) float sh2[8][32];
    float* sh1p = sh1[half];
    float* sh2p = sh2[half];

    // ---- per-lane weight rows (registers) ----
    float wih0[16], whh0[32], wih1[32], whh1[32];
#pragma unroll
    for (int q = 0; q < 4; ++q) {
        float4 v = reinterpret_cast<const float4*>(Wih0 + j * 16)[q];
        wih0[4*q+0] = v.x; wih0[4*q+1] = v.y; wih0[4*q+2] = v.z; wih0[4*q+3] = v.w;
    }
#pragma unroll
    for (int q = 0; q < 8; ++q) {
        float4 a = reinterpret_cast<const float4*>(Whh0 + j * 32)[q];
        whh0[4*q+0] = a.x; whh0[4*q+1] = a.y; whh0[4*q+2] = a.z; whh0[4*q+3] = a.w;
        float4 b = reinterpret_cast<const float4*>(Wih1 + j * 32)[q];
        wih1[4*q+0] = b.x; wih1[4*q+1] = b.y; wih1[4*q+2] = b.z; wih1[4*q+3] = b.w;
        float4 c = reinterpret_cast<const float4*>(Whh1 + j * 32)[q];
        whh1[4*q+0] = c.x; whh1[4*q+1] = c.y; whh1[4*q+2] = c.z; whh1[4*q+3] = c.w;
    }
    const float bias0 = bih0[j] + bhh0[j];
    const float bias1 = bih1[j] + bhh1[j];

    const float* xrow = x + (size_t)batch * (T_DIM * I_DIM);

    // replicated hidden-state vectors
    float h1v[32], h2v[32];
#pragma unroll
    for (int k = 0; k < 32; ++k) h2v[k] = 0.f;   // h2(-1) = 0

    // ---- prologue: h1(0) = tanh(xb(0)), then xb1 = xb(1) ----
    float xb1;
    {
        float4 a = reinterpret_cast<const float4*>(xrow)[0];
        float4 b = reinterpret_cast<const float4*>(xrow)[1];
        float4 c = reinterpret_cast<const float4*>(xrow)[2];
        float4 d = reinterpret_cast<const float4*>(xrow)[3];
        float p = bias0, q = 0.f, r = 0.f, s = 0.f;
        p = fmaf(wih0[0],  a.x, p); q = fmaf(wih0[1],  a.y, q);
        r = fmaf(wih0[2],  a.z, r); s = fmaf(wih0[3],  a.w, s);
        p = fmaf(wih0[4],  b.x, p); q = fmaf(wih0[5],  b.y, q);
        r = fmaf(wih0[6],  b.z, r); s = fmaf(wih0[7],  b.w, s);
        p = fmaf(wih0[8],  c.x, p); q = fmaf(wih0[9],  c.y, q);
        r = fmaf(wih0[10], c.z, r); s = fmaf(wih0[11], c.w, s);
        p = fmaf(wih0[12], d.x, p); q = fmaf(wih0[13], d.y, q);
        r = fmaf(wih0[14], d.z, r); s = fmaf(wih0[15], d.w, s);
        float h10 = fast_tanh((p + q) + (r + s));
        sh1p[j] = h10;
        __builtin_amdgcn_wave_barrier();
#pragma unroll
        for (int q2 = 0; q2 < 8; ++q2) {
            float4 v = reinterpret_cast<const float4*>(sh1p)[q2];
            h1v[4*q2+0] = v.x; h1v[4*q2+1] = v.y; h1v[4*q2+2] = v.z; h1v[4*q2+3] = v.w;
        }
        // xb(1)
        float4 e = reinterpret_cast<const float4*>(xrow + I_DIM)[0];
        float4 f = reinterpret_cast<const float4*>(xrow + I_DIM)[1];
        float4 g = reinterpret_cast<const float4*>(xrow + I_DIM)[2];
        float4 h = reinterpret_cast<const float4*>(xrow + I_DIM)[3];
        float u0 = bias0, u1 = 0.f, u2 = 0.f, u3 = 0.f;
        u0 = fmaf(wih0[0],  e.x, u0); u1 = fmaf(wih0[1],  e.y, u1);
        u2 = fmaf(wih0[2],  e.z, u2); u3 = fmaf(wih0[3],  e.w, u3);
        u0 = fmaf(wih0[4],  f.x, u0); u1 = fmaf(wih0[5],  f.y, u1);
        u2 = fmaf(wih0[6],  f.z, u2); u3 = fmaf(wih0[7],  f.w, u3);
        u0 = fmaf(wih0[8],  g.x, u0); u1 = fmaf(wih0[9],  g.y, u1);
        u2 = fmaf(wih0[10], g.z, u2); u3 = fmaf(wih0[11], g.w, u3);
        u0 = fmaf(wih0[12], h.x, u0); u1 = fmaf(wih0[13], h.y, u1);
        u2 = fmaf(wih0[14], h.z, u2); u3 = fmaf(wih0[15], h.w, u3);
        xb1 = (u0 + u1) + (u2 + u3);
    }

    // ---- main loop: iter t computes h1(t+1) and h2(t) ----
#pragma unroll 1
    for (int t = 0; t < T_DIM; ++t) {
        // issue prefetch of x(t+2) early (feeds next iteration's xb fold)
        const int tn = (t + 2 < T_DIM) ? (t + 2) : (T_DIM - 1);
        const float4* xp = reinterpret_cast<const float4*>(xrow + (size_t)tn * I_DIM);
        float4 nx0 = xp[0];
        float4 nx1 = xp[1];
        float4 nx2 = xp[2];
        float4 nx3 = xp[3];

        // two independent dots from the same h1v (+ h2v), 8 accumulators
        float p0 = xb1,   q0 = 0.f, r0 = 0.f, s0 = 0.f;   // layer 0, step t+1
        float p1 = bias1, q1 = 0.f, r1 = 0.f, s1 = 0.f;   // layer 1, step t
#pragma unroll
        for (int k = 0; k < 32; k += 4) {
            p0 = fmaf(whh0[k+0], h1v[k+0], p0);
            q0 = fmaf(whh0[k+1], h1v[k+1], q0);
            r0 = fmaf(whh0[k+2], h1v[k+2], r0);
            s0 = fmaf(whh0[k+3], h1v[k+3], s0);
            p1 = fmaf(wih1[k+0], h1v[k+0], p1);
            q1 = fmaf(wih1[k+1], h1v[k+1], q1);
            r1 = fmaf(wih1[k+2], h1v[k+2], r1);
            s1 = fmaf(wih1[k+3], h1v[k+3], s1);
            p1 = fmaf(whh1[k+0], h2v[k+0], p1);
            q1 = fmaf(whh1[k+1], h2v[k+1], q1);
            r1 = fmaf(whh1[k+2], h2v[k+2], r1);
            s1 = fmaf(whh1[k+3], h2v[k+3], s1);
        }
        float h1n = fast_tanh((p0 + q0) + (r0 + s0));   // h1(t+1)[j]
        float h2n = fast_tanh((p1 + q1) + (r1 + s1));   // h2(t)[j]

        // single merged transpose phase
        sh1p[j] = h1n;
        sh2p[j] = h2n;
        __builtin_amdgcn_wave_barrier();
#pragma unroll
        for (int q = 0; q < 8; ++q) {
            float4 v1 = reinterpret_cast<const float4*>(sh1p)[q];
            h1v[4*q+0] = v1.x; h1v[4*q+1] = v1.y; h1v[4*q+2] = v1.z; h1v[4*q+3] = v1.w;
            float4 v2 = reinterpret_cast<const float4*>(sh2p)[q];
            h2v[4*q+0] = v2.x; h2v[4*q+1] = v2.y; h2v[4*q+2] = v2.z; h2v[4*q+3] = v2.w;
        }

        // fold prefetched x(t+2) into xb for next iteration (independent filler)
        float a0 = bias0, a1 = 0.f, a2 = 0.f, a3 = 0.f;
        a0 = fmaf(wih0[0],  nx0.x, a0); a1 = fmaf(wih0[1],  nx0.y, a1);
        a2 = fmaf(wih0[2],  nx0.z, a2); a3 = fmaf(wih0[3],  nx0.w, a3);
        a0 = fmaf(wih0[4],  nx1.x, a0); a1 = fmaf(wih0[5],  nx1.y, a1);
        a2 = fmaf(wih0[6],  nx1.z, a2); a3 = fmaf(wih0[7],  nx1.w, a3);
        a0 = fmaf(wih0[8],  nx2.x, a0); a1 = fmaf(wih0[9],  nx2.y, a1);
        a2 = fmaf(wih0[10], nx2.z, a2); a3 = fmaf(wih0[11], nx2.w, a3);
        a0 = fmaf(wih0[12], nx3.x, a0); a1 = fmaf(wih0[13], nx3.y, a1);
        a2 = fmaf(wih0[14], nx3.z, a2); a3 = fmaf(wih0[15], nx3.w, a3);
        xb1 = (a0 + a1) + (a2 + a3);
    }

    // ---- final FC: logits[b] = fc_w . h2(T-1) + fc_b ----
    float fw[32];
#pragma unroll
    for (int q = 0; q < 8; ++q) {
        float4 v = reinterpret_cast<const float4*>(fcw)[q];
        fw[4*q+0] = v.x; fw[4*q+1] = v.y; fw[4*q+2] = v.z; fw[4*q+3] = v.w;
    }
    float r0 = 0.f, r1 = 0.f, r2 = 0.f, r3 = 0.f;
#pragma unroll
    for (int k = 0; k < 32; k += 4) {
        r0 = fmaf(fw[k+0], h2v[k+0], r0);
        r1 = fmaf(fw[k+1], h2v[k+1], r1);
        r2 = fmaf(fw[k+2], h2v[k+2], r2);
        r3 = fmaf(fw[k+3], h2v[k+3], r3);
    }
    float logit = fcb[0] + (r0 + r1) + (r2 + r3);
    if (j == 0) out[batch] = logit;
}

extern "C" void kernel_launch(void* const* d_in, const int* in_sizes, int n_in,
                              void* d_out, int out_size, void* d_ws, size_t ws_size,
                              hipStream_t stream) {
    const float* x    = (const float*)d_in[0];
    const float* Wih0 = (const float*)d_in[1];
    const float* Whh0 = (const float*)d_in[2];
    const float* bih0 = (const float*)d_in[3];
    const float* bhh0 = (const float*)d_in[4];
    const float* Wih1 = (const float*)d_in[5];
    const float* Whh1 = (const float*)d_in[6];
    const float* bih1 = (const float*)d_in[7];
    const float* bhh1 = (const float*)d_in[8];
    const float* fcw  = (const float*)d_in[9];
    const float* fcb  = (const float*)d_in[10];
    float* out = (float*)d_out;

    dim3 grid(B_DIM / 8);   // 512 blocks x 256 threads = 4096 half-waves
    rnn2_pipe_kernel<<<grid, 256, 0, stream>>>(x, Wih0, Whh0, bih0, bhh0,
                                               Wih1, Whh1, bih1, bhh1,
                                               fcw, fcb, out);
}

// Round 10
// 225.381 us; speedup vs baseline: 2.9714x; 1.4454x over previous
//
#include <hip/hip_runtime.h>

#define I_DIM 16
#define H_DIM 32
#define T_DIM 512
#define B_DIM 4096

typedef __fp16 hf2 __attribute__((ext_vector_type(2)));

__device__ __forceinline__ float fast_tanh(float x) {
    // tanh(x) = 1 - 2/(exp(2x)+1); exp(2x) = exp2(x * 2*log2(e))
    float e = __builtin_amdgcn_exp2f(x * 2.885390081777927f);
    return 1.0f - 2.0f * __builtin_amdgcn_rcpf(e + 1.0f);
}

__device__ __forceinline__ hf2 pack2(float a, float b) {   // setup-path pack
    hf2 r; r[0] = (__fp16)a; r[1] = (__fp16)b; return r;
}
__device__ __forceinline__ hf2 u2h(unsigned u) {           // bitcast u32 -> 2xf16
    union { unsigned u; hf2 h; } c; c.u = u; return c.h;
}

// One batch row per 32-lane half-wave; cross-layer pipeline (round-8 structure);
// ALL operands f16-packed so weights(56) + h1v/h2v(32) + x(8) fit in registers
// and each 32-dot is 16 v_dot2_f32_f16 with f32 accumulation.
__global__ void __launch_bounds__(256)
__attribute__((amdgpu_waves_per_eu(2, 2)))
rnn2_dot2_kernel(const float* __restrict__ x,
                 const float* __restrict__ Wih0, const float* __restrict__ Whh0,
                 const float* __restrict__ bih0, const float* __restrict__ bhh0,
                 const float* __restrict__ Wih1, const float* __restrict__ Whh1,
                 const float* __restrict__ bih1, const float* __restrict__ bhh1,
                 const float* __restrict__ fcw, const float* __restrict__ fcb,
                 float* __restrict__ out)
{
    const int tid  = threadIdx.x;
    const int j    = tid & 31;        // output row within H
    const int half = tid >> 5;        // 0..7: batch element within block
    const int batch = blockIdx.x * 8 + half;

    __shared__ __align__(16) __fp16 sh1[8][32];
    __shared__ __align__(16) __fp16 sh2[8][32];
    __fp16* sh1p = sh1[half];
    __fp16* sh2p = sh2[half];

    // ---- packed per-lane weight rows ----
    hf2 wih0p[8], whh0p[16], wih1p[16], whh1p[16];
#pragma unroll
    for (int q = 0; q < 4; ++q) {
        float4 v = reinterpret_cast<const float4*>(Wih0 + j * 16)[q];
        wih0p[2*q+0] = pack2(v.x, v.y);
        wih0p[2*q+1] = pack2(v.z, v.w);
    }
#pragma unroll
    for (int q = 0; q < 8; ++q) {
        float4 a = reinterpret_cast<const float4*>(Whh0 + j * 32)[q];
        whh0p[2*q+0] = pack2(a.x, a.y); whh0p[2*q+1] = pack2(a.z, a.w);
        float4 b = reinterpret_cast<const float4*>(Wih1 + j * 32)[q];
        wih1p[2*q+0] = pack2(b.x, b.y); wih1p[2*q+1] = pack2(b.z, b.w);
        float4 c = reinterpret_cast<const float4*>(Whh1 + j * 32)[q];
        whh1p[2*q+0] = pack2(c.x, c.y); whh1p[2*q+1] = pack2(c.z, c.w);
    }
    const float bias0 = bih0[j] + bhh0[j];
    const float bias1 = bih1[j] + bhh1[j];

    const float* xrow = x + (size_t)batch * (T_DIM * I_DIM);

    // packed replicated hidden states
    hf2 h1v[16], h2v[16];
#pragma unroll
    for (int k = 0; k < 16; ++k) { h2v[k] = pack2(0.f, 0.f); }

    // ---- prologue: h1(0) = tanh(bias0 + Wih0.x(0)); xb1 = xb(1) ----
    float xb1;
    {
        float4 a = reinterpret_cast<const float4*>(xrow)[0];
        float4 b = reinterpret_cast<const float4*>(xrow)[1];
        float4 c = reinterpret_cast<const float4*>(xrow)[2];
        float4 d = reinterpret_cast<const float4*>(xrow)[3];
        hf2 px[8];
        px[0] = __builtin_amdgcn_cvt_pkrtz(a.x, a.y); px[1] = __builtin_amdgcn_cvt_pkrtz(a.z, a.w);
        px[2] = __builtin_amdgcn_cvt_pkrtz(b.x, b.y); px[3] = __builtin_amdgcn_cvt_pkrtz(b.z, b.w);
        px[4] = __builtin_amdgcn_cvt_pkrtz(c.x, c.y); px[5] = __builtin_amdgcn_cvt_pkrtz(c.z, c.w);
        px[6] = __builtin_amdgcn_cvt_pkrtz(d.x, d.y); px[7] = __builtin_amdgcn_cvt_pkrtz(d.z, d.w);
        float s0 = bias0, s1 = 0.f, s2 = 0.f, s3 = 0.f;
#pragma unroll
        for (int k = 0; k < 8; k += 4) {
            s0 = __builtin_amdgcn_fdot2(wih0p[k+0], px[k+0], s0, false);
            s1 = __builtin_amdgcn_fdot2(wih0p[k+1], px[k+1], s1, false);
            s2 = __builtin_amdgcn_fdot2(wih0p[k+2], px[k+2], s2, false);
            s3 = __builtin_amdgcn_fdot2(wih0p[k+3], px[k+3], s3, false);
        }
        float h10 = fast_tanh((s0 + s1) + (s2 + s3));
        sh1p[j] = (__fp16)h10;
        __builtin_amdgcn_wave_barrier();
#pragma unroll
        for (int q = 0; q < 4; ++q) {
            uint4 v = reinterpret_cast<const uint4*>(sh1p)[q];
            h1v[4*q+0] = u2h(v.x); h1v[4*q+1] = u2h(v.y);
            h1v[4*q+2] = u2h(v.z); h1v[4*q+3] = u2h(v.w);
        }
        // xb(1)
        float4 e = reinterpret_cast<const float4*>(xrow + I_DIM)[0];
        float4 f = reinterpret_cast<const float4*>(xrow + I_DIM)[1];
        float4 g = reinterpret_cast<const float4*>(xrow + I_DIM)[2];
        float4 h = reinterpret_cast<const float4*>(xrow + I_DIM)[3];
        hf2 qx[8];
        qx[0] = __builtin_amdgcn_cvt_pkrtz(e.x, e.y); qx[1] = __builtin_amdgcn_cvt_pkrtz(e.z, e.w);
        qx[2] = __builtin_amdgcn_cvt_pkrtz(f.x, f.y); qx[3] = __builtin_amdgcn_cvt_pkrtz(f.z, f.w);
        qx[4] = __builtin_amdgcn_cvt_pkrtz(g.x, g.y); qx[5] = __builtin_amdgcn_cvt_pkrtz(g.z, g.w);
        qx[6] = __builtin_amdgcn_cvt_pkrtz(h.x, h.y); qx[7] = __builtin_amdgcn_cvt_pkrtz(h.z, h.w);
        float u0 = bias0, u1 = 0.f, u2 = 0.f, u3 = 0.f;
#pragma unroll
        for (int k = 0; k < 8; k += 4) {
            u0 = __builtin_amdgcn_fdot2(wih0p[k+0], qx[k+0], u0, false);
            u1 = __builtin_amdgcn_fdot2(wih0p[k+1], qx[k+1], u1, false);
            u2 = __builtin_amdgcn_fdot2(wih0p[k+2], qx[k+2], u2, false);
            u3 = __builtin_amdgcn_fdot2(wih0p[k+3], qx[k+3], u3, false);
        }
        xb1 = (u0 + u1) + (u2 + u3);
    }

    // ---- main loop: iter t computes h1(t+1) and h2(t) ----
#pragma unroll 1
    for (int t = 0; t < T_DIM; ++t) {
        const int tn = (t + 2 < T_DIM) ? (t + 2) : (T_DIM - 1);
        const float4* xp = reinterpret_cast<const float4*>(xrow + (size_t)tn * I_DIM);
        float4 nx0 = xp[0];
        float4 nx1 = xp[1];
        float4 nx2 = xp[2];
        float4 nx3 = xp[3];

        // layer 0 (step t+1) and layer 1 (step t) dots, 8 f32 accumulators
        float a0 = xb1,   a1 = 0.f, a2 = 0.f, a3 = 0.f;
        float c0 = bias1, c1 = 0.f, c2 = 0.f, c3 = 0.f;
#pragma unroll
        for (int k = 0; k < 16; k += 4) {
            a0 = __builtin_amdgcn_fdot2(whh0p[k+0], h1v[k+0], a0, false);
            a1 = __builtin_amdgcn_fdot2(whh0p[k+1], h1v[k+1], a1, false);
            a2 = __builtin_amdgcn_fdot2(whh0p[k+2], h1v[k+2], a2, false);
            a3 = __builtin_amdgcn_fdot2(whh0p[k+3], h1v[k+3], a3, false);
            c0 = __builtin_amdgcn_fdot2(wih1p[k+0], h1v[k+0], c0, false);
            c1 = __builtin_amdgcn_fdot2(wih1p[k+1], h1v[k+1], c1, false);
            c2 = __builtin_amdgcn_fdot2(wih1p[k+2], h1v[k+2], c2, false);
            c3 = __builtin_amdgcn_fdot2(wih1p[k+3], h1v[k+3], c3, false);
            c0 = __builtin_amdgcn_fdot2(whh1p[k+0], h2v[k+0], c0, false);
            c1 = __builtin_amdgcn_fdot2(whh1p[k+1], h2v[k+1], c1, false);
            c2 = __builtin_amdgcn_fdot2(whh1p[k+2], h2v[k+2], c2, false);
            c3 = __builtin_amdgcn_fdot2(whh1p[k+3], h2v[k+3], c3, false);
        }
        float h1n = fast_tanh((a0 + a1) + (a2 + a3));   // h1(t+1)[j]
        float h2n = fast_tanh((c0 + c1) + (c2 + c3));   // h2(t)[j]

        // single merged transpose phase (f16: 64B rows, 4 b128 reads each)
        sh1p[j] = (__fp16)h1n;
        sh2p[j] = (__fp16)h2n;
        __builtin_amdgcn_wave_barrier();
#pragma unroll
        for (int q = 0; q < 4; ++q) {
            uint4 v1 = reinterpret_cast<const uint4*>(sh1p)[q];
            h1v[4*q+0] = u2h(v1.x); h1v[4*q+1] = u2h(v1.y);
            h1v[4*q+2] = u2h(v1.z); h1v[4*q+3] = u2h(v1.w);
            uint4 v2 = reinterpret_cast<const uint4*>(sh2p)[q];
            h2v[4*q+0] = u2h(v2.x); h2v[4*q+1] = u2h(v2.y);
            h2v[4*q+2] = u2h(v2.z); h2v[4*q+3] = u2h(v2.w);
        }

        // fold x(t+2) into xb for next iteration (off critical path)
        hf2 px[8];
        px[0] = __builtin_amdgcn_cvt_pkrtz(nx0.x, nx0.y);
        px[1] = __builtin_amdgcn_cvt_pkrtz(nx0.z, nx0.w);
        px[2] = __builtin_amdgcn_cvt_pkrtz(nx1.x, nx1.y);
        px[3] = __builtin_amdgcn_cvt_pkrtz(nx1.z, nx1.w);
        px[4] = __builtin_amdgcn_cvt_pkrtz(nx2.x, nx2.y);
        px[5] = __builtin_amdgcn_cvt_pkrtz(nx2.z, nx2.w);
        px[6] = __builtin_amdgcn_cvt_pkrtz(nx3.x, nx3.y);
        px[7] = __builtin_amdgcn_cvt_pkrtz(nx3.z, nx3.w);
        float b0 = bias0, b1 = 0.f, b2 = 0.f, b3 = 0.f;
#pragma unroll
        for (int k = 0; k < 8; k += 4) {
            b0 = __builtin_amdgcn_fdot2(wih0p[k+0], px[k+0], b0, false);
            b1 = __builtin_amdgcn_fdot2(wih0p[k+1], px[k+1], b1, false);
            b2 = __builtin_amdgcn_fdot2(wih0p[k+2], px[k+2], b2, false);
            b3 = __builtin_amdgcn_fdot2(wih0p[k+3], px[k+3], b3, false);
        }
        xb1 = (b0 + b1) + (b2 + b3);
    }

    // ---- final FC: logits[b] = fc_w . h2(T-1) + fc_b ----
    hf2 fwp[16];
#pragma unroll
    for (int q = 0; q < 8; ++q) {
        float4 v = reinterpret_cast<const float4*>(fcw)[q];
        fwp[2*q+0] = pack2(v.x, v.y);
        fwp[2*q+1] = pack2(v.z, v.w);
    }
    float r0 = 0.f, r1 = 0.f, r2 = 0.f, r3 = 0.f;
#pragma unroll
    for (int k = 0; k < 16; k += 4) {
        r0 = __builtin_amdgcn_fdot2(fwp[k+0], h2v[k+0], r0, false);
        r1 = __builtin_amdgcn_fdot2(fwp[k+1], h2v[k+1], r1, false);
        r2 = __builtin_amdgcn_fdot2(fwp[k+2], h2v[k+2], r2, false);
        r3 = __builtin_amdgcn_fdot2(fwp[k+3], h2v[k+3], r3, false);
    }
    float logit = fcb[0] + (r0 + r1) + (r2 + r3);
    if (j == 0) out[batch] = logit;
}

extern "C" void kernel_launch(void* const* d_in, const int* in_sizes, int n_in,
                              void* d_out, int out_size, void* d_ws, size_t ws_size,
                              hipStream_t stream) {
    const float* x    = (const float*)d_in[0];
    const float* Wih0 = (const float*)d_in[1];
    const float* Whh0 = (const float*)d_in[2];
    const float* bih0 = (const float*)d_in[3];
    const float* bhh0 = (const float*)d_in[4];
    const float* Wih1 = (const float*)d_in[5];
    const float* Whh1 = (const float*)d_in[6];
    const float* bih1 = (const float*)d_in[7];
    const float* bhh1 = (const float*)d_in[8];
    const float* fcw  = (const float*)d_in[9];
    const float* fcb  = (const float*)d_in[10];
    float* out = (float*)d_out;

    dim3 grid(B_DIM / 8);   // 512 blocks x 256 threads = 4096 half-waves
    rnn2_dot2_kernel<<<grid, 256, 0, stream>>>(x, Wih0, Whh0, bih0, bhh0,
                                               Wih1, Whh1, bih1, bhh1,
                                               fcw, fcb, out);
}